// Round 2
// baseline (170.138 us; speedup 1.0000x reference)
//
#include <hip/hip_runtime.h>
#include <hip/hip_bf16.h>

typedef __attribute__((ext_vector_type(8))) short short8;
typedef __attribute__((ext_vector_type(8))) unsigned short ushort8;
typedef __attribute__((ext_vector_type(4))) float floatx4;

#define L2E 1.4426950408889634f

#if __has_builtin(__builtin_amdgcn_exp2f)
#define EXP2(x) __builtin_amdgcn_exp2f(x)
#else
#define EXP2(x) exp2f(x)
#endif
#if __has_builtin(__builtin_amdgcn_rcpf)
#define RCP(x) __builtin_amdgcn_rcpf(x)
#else
#define RCP(x) (1.0f / (x))
#endif

static __device__ __forceinline__ unsigned short f2bf(float f) {
    unsigned int u = __builtin_bit_cast(unsigned int, f);
    u += 0x7fffu + ((u >> 16) & 1u);   // RNE
    return (unsigned short)(u >> 16);
}
static __device__ __forceinline__ unsigned int pk_bf16(float a, float b) {
    __hip_bfloat162 h2 = __float22bfloat162_rn(make_float2(a, b));   // v_cvt_pk_bf16_f32
    unsigned int u;
    __builtin_memcpy(&u, &h2, 4);     // low16 = a, high16 = b
    return u;
}

// ---------------- 1) QKV GEMM, self-staging (unchanged) ----------------
__global__ __launch_bounds__(256) void k_qkv(const float* __restrict__ x,
                                             const float* __restrict__ qw,
                                             unsigned short* __restrict__ qm,
                                             unsigned short* __restrict__ km,
                                             unsigned short* __restrict__ vt) {
    __shared__ __align__(16) unsigned short At[64][136];
    __shared__ __align__(16) unsigned short Wt[64][136];
    const int tid = threadIdx.x;
    const int wave = tid >> 6, lane = tid & 63;
    const int l16 = lane & 15, quad = lane >> 4;
    const int m0 = blockIdx.x * 64;
    const int o0 = blockIdx.y * 64;

    floatx4 acc[4] = {};
    for (int rnd = 0; rnd < 2; ++rnd) {
        const int cbase = rnd * 128;
        if (rnd) __syncthreads();
        {
            const int moff = (tid & 3) * 16;
            #pragma unroll
            for (int half = 0; half < 2; ++half) {
                const int c_l = (tid >> 2) + 64 * half;
                const float4* xp = reinterpret_cast<const float4*>(
                    x + (size_t)(cbase + c_l) * 4096 + m0 + moff);
                const float4 f0 = xp[0], f1 = xp[1], f2 = xp[2], f3 = xp[3];
                At[moff +  0][c_l] = f2bf(f0.x); At[moff +  1][c_l] = f2bf(f0.y);
                At[moff +  2][c_l] = f2bf(f0.z); At[moff +  3][c_l] = f2bf(f0.w);
                At[moff +  4][c_l] = f2bf(f1.x); At[moff +  5][c_l] = f2bf(f1.y);
                At[moff +  6][c_l] = f2bf(f1.z); At[moff +  7][c_l] = f2bf(f1.w);
                At[moff +  8][c_l] = f2bf(f2.x); At[moff +  9][c_l] = f2bf(f2.y);
                At[moff + 10][c_l] = f2bf(f2.z); At[moff + 11][c_l] = f2bf(f2.w);
                At[moff + 12][c_l] = f2bf(f3.x); At[moff + 13][c_l] = f2bf(f3.y);
                At[moff + 14][c_l] = f2bf(f3.z); At[moff + 15][c_l] = f2bf(f3.w);
            }
        }
        {
            const int o_l = tid >> 2, cp = (tid & 3) * 32;
            const float4* wp = reinterpret_cast<const float4*>(
                qw + (size_t)(o0 + o_l) * 256 + cbase + cp);
            #pragma unroll
            for (int j = 0; j < 2; ++j) {
                const float4 g0 = wp[4 * j + 0], g1 = wp[4 * j + 1];
                const float4 g2 = wp[4 * j + 2], g3 = wp[4 * j + 3];
                unsigned int u[8];
                u[0] = pk_bf16(g0.x, g0.y); u[1] = pk_bf16(g0.z, g0.w);
                u[2] = pk_bf16(g1.x, g1.y); u[3] = pk_bf16(g1.z, g1.w);
                u[4] = pk_bf16(g2.x, g2.y); u[5] = pk_bf16(g2.z, g2.w);
                u[6] = pk_bf16(g3.x, g3.y); u[7] = pk_bf16(g3.z, g3.w);
                __builtin_memcpy(&Wt[o_l][cp + 16 * j], u, 32);
            }
        }
        __syncthreads();
        #pragma unroll
        for (int cc = 0; cc < 4; ++cc) {
            const int c0 = cc * 32 + quad * 8;
            const short8 a = *reinterpret_cast<const short8*>(&At[wave * 16 + l16][c0]);
            #pragma unroll
            for (int t4 = 0; t4 < 4; ++t4) {
                const short8 b = *reinterpret_cast<const short8*>(&Wt[t4 * 16 + l16][c0]);
                acc[t4] = __builtin_amdgcn_mfma_f32_16x16x32_bf16(a, b, acc[t4], 0, 0, 0);
            }
        }
    }
    const float qscale = 0.17677669529663687f * L2E;
    #pragma unroll
    for (int t4 = 0; t4 < 4; ++t4) {
        #pragma unroll
        for (int r = 0; r < 4; ++r) {
            const int n = m0 + wave * 16 + quad * 4 + r;
            const int o = o0 + t4 * 16 + l16;
            const int s = o >> 8, rem = o & 255, head = rem >> 5, t = rem & 31;
            if (s == 0)       qm[((size_t)head * 4096 + n) * 32 + t] = f2bf(acc[t4][r] * qscale);
            else if (s == 1)  km[((size_t)head * 4096 + n) * 32 + t] = f2bf(acc[t4][r]);
            else              vt[((size_t)head * 32 + t) * 4096 + n] = f2bf(acc[t4][r]);
        }
    }
}

// ---------------- 2) flash attention: S^T form, period-3 name-rotated pipeline ----------------
// R17: the R15/R16 pipeline rotated state through array copies (kb=kn etc.) with
// guarded loads; LLVM sank every global load to its use (VGPR_Count 36 even with a
// 128-reg budget) -> load-to-use distance 0, every tile serialized on L2/L3 latency
// (MfmaUtil 5%, VALUBusy 20%, 75% idle). Fix: 3 explicit state sets S0/S1/S2 and a
// period-3 unrolled loop BODY(P,C,N) -- no rotation copies, plain PHIs, so the
// scheduler can keep K one iteration and V two iterations in flight.
// launch_bounds(256,3): 168-VGPR budget so regalloc never re-sinks; 3 blocks/CU
// resident + queued spares backfill the load-imbalance tail.
__global__ __launch_bounds__(256, 3) void k_attn(const unsigned short* __restrict__ qm,
                                              const unsigned short* __restrict__ km,
                                              const unsigned short* __restrict__ vt,
                                              unsigned short* __restrict__ ao) {
    const int h   = blockIdx.y;
    const int nq0 = blockIdx.x * 16;
    const int tid = threadIdx.x;
    const int wv  = __builtin_amdgcn_readfirstlane(tid >> 6);   // scalar: scan stays SALU
    const int lane = tid & 63;
    const int l16 = lane & 15, quad = lane >> 4;

    __shared__ __align__(16) char smem[4][4608];
    typedef unsigned short ptrow_t[16][72];   // one PT buffer: 16 q-rows x 72 (2304 B)
    ptrow_t* PTw = reinterpret_cast<ptrow_t*>(smem[wv]);        // PTw[buf][q][key]

    // B-operand for S^T: Q^T (n=q on l16, k=c on quad*8+j)
    const short8 a_q = *reinterpret_cast<const short8*>(
        qm + ((size_t)h * 4096 + nq0 + l16) * 32 + quad * 8);

    const int hq = (nq0 >> 4) & 15, dq = nq0 >> 8;
    float dw2[4];
    #pragma unroll
    for (int r = 0; r < 4; ++r) {
        const float dw = (float)(quad * 4 + r - l16);   // key_w - q_w (symmetric form)
        dw2[r] = dw * dw;
    }

    const unsigned short* kmh = km + ((size_t)h << 17) + l16 * 32 + quad * 8;
    const unsigned short* vt0 = vt + ((size_t)(h * 32 + l16) << 12) + quad * 8;
    const unsigned short* vt1 = vt0 + (16 << 12);

    float l_acc = 0.f;
    floatx4 o_acc[2] = {};

    int jt = -1, c = 0;

#define SCAN(J0, THR)                                                     \
    J0 = -1;                                                              \
    while (++jt < 64) {                                                   \
        const int dk = jt >> 2, hk0 = (jt & 3) * 4;                       \
        const int dd = dq - dk;                                           \
        int dh = 0;                                                      \
        if (hq < hk0) dh = hk0 - hq;                                      \
        else if (hq > hk0 + 3) dh = hq - hk0 - 3;                         \
        if (dd * dd + dh * dh >= 100) continue;                           \
        if (((c++) & 3) != wv) continue;                                  \
        J0 = jt * 64;                                                     \
        const int bb = 100 - dd * dd;                                     \
        THR[0] = bb - (hq - hk0) * (hq - hk0);                            \
        THR[1] = bb - (hq - hk0 - 1) * (hq - hk0 - 1);                    \
        THR[2] = bb - (hq - hk0 - 2) * (hq - hk0 - 2);                    \
        THR[3] = bb - (hq - hk0 - 3) * (hq - hk0 - 3);                    \
        break;                                                            \
    }

// S/exp/PT-write stage for tile (THR,KB) into buffer BUF
#define SSTAGE(THR, KB, BUF)                                              \
    {                                                                     \
        _Pragma("unroll")                                                 \
        for (int t4 = 0; t4 < 4; ++t4) {                                  \
            const bool sib = (THR[t4 ^ 1] > 0);                           \
            if (THR[t4] > 0) {                                            \
                const floatx4 sf = __builtin_amdgcn_mfma_f32_16x16x32_bf16( \
                    KB[t4], a_q, (floatx4){0.f, 0.f, 0.f, 0.f}, 0, 0, 0); \
                const float thrf = (float)THR[t4];                        \
                const float p0 = (dw2[0] < thrf) ? EXP2(sf[0]) : 0.f;     \
                const float p1 = (dw2[1] < thrf) ? EXP2(sf[1]) : 0.f;     \
                const float p2 = (dw2[2] < thrf) ? EXP2(sf[2]) : 0.f;     \
                const float p3 = (dw2[3] < thrf) ? EXP2(sf[3]) : 0.f;     \
                l_acc += (p0 + p1) + (p2 + p3);                           \
                unsigned int pair[2];                                     \
                pair[0] = pk_bf16(p0, p1);                                \
                pair[1] = pk_bf16(p2, p3);                                \
                __builtin_memcpy(&PTw[BUF][l16][t4 * 16 + quad * 4], pair, 8); \
            } else if (sib) {                                             \
                const unsigned int zz[2] = {0u, 0u};                      \
                __builtin_memcpy(&PTw[BUF][l16][t4 * 16 + quad * 4], zz, 8); \
            }                                                             \
        }                                                                 \
    }

// Load K (4x short8) and V (4x short8) for state set N
#define KVLOAD(N)                                                         \
    if (j0_##N >= 0) {                                                    \
        _Pragma("unroll")                                                 \
        for (int t4 = 0; t4 < 4; ++t4)                                    \
            k_##N[t4] = *reinterpret_cast<const short8*>(                 \
                kmh + ((j0_##N + t4 * 16) << 5));                         \
        v_##N[0] = *reinterpret_cast<const short8*>(vt0 + j0_##N);        \
        v_##N[1] = *reinterpret_cast<const short8*>(vt1 + j0_##N);        \
        v_##N[2] = *reinterpret_cast<const short8*>(vt0 + j0_##N + 32);   \
        v_##N[3] = *reinterpret_cast<const short8*>(vt1 + j0_##N + 32);   \
    }

// One pipeline step: P = PV-ready (PT in PTw[pb], V held), C = K/V held (S pending),
// N = to be scanned + loads issued. V load->use distance ~2 iterations.
#define BODY(P, C, N)                                                     \
    if (j0_##P < 0) break;                                                \
    SCAN(j0_##N, thr_##N)                                                 \
    KVLOAD(N)                                                             \
    if (j0_##C >= 0) SSTAGE(thr_##C, k_##C, pb ^ 1)                       \
    _Pragma("unroll")                                                     \
    for (int kt = 0; kt < 2; ++kt) {                                      \
        if (thr_##P[2 * kt] > 0 || thr_##P[2 * kt + 1] > 0) {             \
            const short8 b_p = *reinterpret_cast<const short8*>(          \
                &PTw[pb][l16][kt * 32 + quad * 8]);                       \
            o_acc[0] = __builtin_amdgcn_mfma_f32_16x16x32_bf16(           \
                v_##P[2 * kt], b_p, o_acc[0], 0, 0, 0);                   \
            o_acc[1] = __builtin_amdgcn_mfma_f32_16x16x32_bf16(           \
                v_##P[2 * kt + 1], b_p, o_acc[1], 0, 0, 0);               \
        }                                                                 \
    }                                                                     \
    pb ^= 1;

    // ---- pipeline state: three explicit sets, no rotation copies ----
    int j0_0 = -1, j0_1 = -1, j0_2 = -1;
    int thr_0[4] = {}, thr_1[4] = {}, thr_2[4] = {};
    short8 k_0[4] = {}, k_1[4] = {}, k_2[4] = {};
    short8 v_0[4] = {}, v_1[4] = {}, v_2[4] = {};
    int pb = 0;

    // prologue: S0 scanned+loaded+S-staged into buffer 0; S1 scanned+loaded
    SCAN(j0_0, thr_0)
    KVLOAD(0)
    if (j0_0 >= 0) SSTAGE(thr_0, k_0, 0)
    SCAN(j0_1, thr_1)
    KVLOAD(1)

    for (;;) {
        BODY(0, 1, 2)
        BODY(1, 2, 0)
        BODY(2, 0, 1)
    }
#undef BODY
#undef KVLOAD
#undef SSTAGE
#undef SCAN

    // ---- epilogue: reuse this wave's smem region for O/l partials ----
    float (*obufw)[20] = reinterpret_cast<float(*)[20]>(smem[wv]);   // [32][20], 2560 B
    float* lbufw = reinterpret_cast<float*>(smem[wv] + 2560);        // [16]

    // l: per-lane scalar; sum over quads (lanes sharing l16)
    l_acc += __shfl_xor(l_acc, 16);
    l_acc += __shfl_xor(l_acc, 32);
    if (lane < 16) lbufw[l16] = l_acc;
    #pragma unroll
    for (int tt = 0; tt < 2; ++tt)
        #pragma unroll
        for (int r = 0; r < 4; ++r)
            obufw[tt * 16 + quad * 4 + r][l16] = o_acc[tt][r];
    __syncthreads();

    // combine waves, normalize, write (q = tid&15, d pair = (tid>>4)*2)
    const int q = tid & 15, d0 = (tid >> 4) * 2;
    float lt = 0.f, oa = 0.f, ob = 0.f;
    #pragma unroll
    for (int w = 0; w < 4; ++w) {
        const float (*obw)[20] = reinterpret_cast<const float(*)[20]>(smem[w]);
        lt += reinterpret_cast<const float*>(smem[w] + 2560)[q];
        oa += obw[d0][q];
        ob += obw[d0 + 1][q];
    }
    const float inv = RCP(lt);
    const unsigned int uo = pk_bf16(oa * inv, ob * inv);
    *reinterpret_cast<unsigned int*>(ao + (size_t)(nq0 + q) * 256 + h * 32 + d0) = uo;
}

// ---------------- 3) proj GEMM + bias, self-staging pw (unchanged) ----------------
__global__ __launch_bounds__(256) void k_proj(const unsigned short* __restrict__ ao,
                                              const float* __restrict__ pw,
                                              const float* __restrict__ pb,
                                              float* __restrict__ out) {
    __shared__ __align__(16) unsigned short Pt[64][264];
    const int tid = threadIdx.x;
    const int wave = tid >> 6, lane = tid & 63;
    const int l16 = lane & 15, quad = lane >> 4;
    const int n0 = blockIdx.x * 64;
    const int m0 = blockIdx.y * 64;

    {
        const int o_l = tid >> 2, cp = (tid & 3) * 64;
        const float4* wp = reinterpret_cast<const float4*>(pw + (size_t)(m0 + o_l) * 256 + cp);
        #pragma unroll
        for (int j = 0; j < 4; ++j) {
            const float4 g0 = wp[4 * j + 0], g1 = wp[4 * j + 1];
            const float4 g2 = wp[4 * j + 2], g3 = wp[4 * j + 3];
            unsigned int u[8];
            u[0] = pk_bf16(g0.x, g0.y); u[1] = pk_bf16(g0.z, g0.w);
            u[2] = pk_bf16(g1.x, g1.y); u[3] = pk_bf16(g1.z, g1.w);
            u[4] = pk_bf16(g2.x, g2.y); u[5] = pk_bf16(g2.z, g2.w);
            u[6] = pk_bf16(g3.x, g3.y); u[7] = pk_bf16(g3.z, g3.w);
            __builtin_memcpy(&Pt[o_l][cp + 16 * j], u, 32);
        }
    }
    __syncthreads();

    floatx4 acc[4] = {};
    #pragma unroll
    for (int cc = 0; cc < 8; ++cc) {
        const int c0 = cc * 32 + quad * 8;
        const short8 a = *reinterpret_cast<const short8*>(&Pt[wave * 16 + l16][c0]);
        #pragma unroll
        for (int t4 = 0; t4 < 4; ++t4) {
            const short8 b = *reinterpret_cast<const short8*>(
                ao + (size_t)(n0 + t4 * 16 + l16) * 256 + c0);
            acc[t4] = __builtin_amdgcn_mfma_f32_16x16x32_bf16(a, b, acc[t4], 0, 0, 0);
        }
    }
    #pragma unroll
    for (int t4 = 0; t4 < 4; ++t4) {
        #pragma unroll
        for (int r = 0; r < 4; ++r) {
            const int o = m0 + wave * 16 + quad * 4 + r;
            const int n = n0 + t4 * 16 + l16;
            out[(size_t)o * 4096 + n] = acc[t4][r] + pb[o];
        }
    }
}

extern "C" void kernel_launch(void* const* d_in, const int* in_sizes, int n_in,
                              void* d_out, int out_size, void* d_ws, size_t ws_size,
                              hipStream_t stream) {
    const float* x      = (const float*)d_in[0];
    const float* qkv_w  = (const float*)d_in[1];
    const float* proj_w = (const float*)d_in[2];
    const float* proj_b = (const float*)d_in[3];
    float* out = (float*)d_out;                    // [256,4096] fp32

    char* B = (char*)d_ws;
    const size_t MB = 1u << 20;
    unsigned short* ao = (unsigned short*)(B);
    unsigned short* qm = (unsigned short*)(B + 2 * MB);
    unsigned short* km = (unsigned short*)(B + 4 * MB);
    unsigned short* vt = (unsigned short*)(B + 6 * MB);

    k_qkv<<<dim3(64, 12), 256, 0, stream>>>(x, qkv_w, qm, km, vt);
    k_attn<<<dim3(256, 8), 256, 0, stream>>>(qm, km, vt, ao);
    k_proj<<<dim3(64, 4), 256, 0, stream>>>(ao, proj_w, proj_b, out);
}

// Round 3
// 169.485 us; speedup vs baseline: 1.0039x; 1.0039x over previous
//
#include <hip/hip_runtime.h>
#include <hip/hip_bf16.h>

typedef __attribute__((ext_vector_type(8))) short short8;
typedef __attribute__((ext_vector_type(8))) unsigned short ushort8;
typedef __attribute__((ext_vector_type(4))) float floatx4;

#define L2E 1.4426950408889634f

#if __has_builtin(__builtin_amdgcn_exp2f)
#define EXP2(x) __builtin_amdgcn_exp2f(x)
#else
#define EXP2(x) exp2f(x)
#endif
#if __has_builtin(__builtin_amdgcn_rcpf)
#define RCP(x) __builtin_amdgcn_rcpf(x)
#else
#define RCP(x) (1.0f / (x))
#endif

static __device__ __forceinline__ unsigned short f2bf(float f) {
    unsigned int u = __builtin_bit_cast(unsigned int, f);
    u += 0x7fffu + ((u >> 16) & 1u);   // RNE
    return (unsigned short)(u >> 16);
}
static __device__ __forceinline__ unsigned int pk_bf16(float a, float b) {
    __hip_bfloat162 h2 = __float22bfloat162_rn(make_float2(a, b));   // v_cvt_pk_bf16_f32
    unsigned int u;
    __builtin_memcpy(&u, &h2, 4);     // low16 = a, high16 = b
    return u;
}

// ---------------- 1) QKV GEMM, self-staging (unchanged) ----------------
__global__ __launch_bounds__(256) void k_qkv(const float* __restrict__ x,
                                             const float* __restrict__ qw,
                                             unsigned short* __restrict__ qm,
                                             unsigned short* __restrict__ km,
                                             unsigned short* __restrict__ vt) {
    __shared__ __align__(16) unsigned short At[64][136];
    __shared__ __align__(16) unsigned short Wt[64][136];
    const int tid = threadIdx.x;
    const int wave = tid >> 6, lane = tid & 63;
    const int l16 = lane & 15, quad = lane >> 4;
    const int m0 = blockIdx.x * 64;
    const int o0 = blockIdx.y * 64;

    floatx4 acc[4] = {};
    for (int rnd = 0; rnd < 2; ++rnd) {
        const int cbase = rnd * 128;
        if (rnd) __syncthreads();
        {
            const int moff = (tid & 3) * 16;
            #pragma unroll
            for (int half = 0; half < 2; ++half) {
                const int c_l = (tid >> 2) + 64 * half;
                const float4* xp = reinterpret_cast<const float4*>(
                    x + (size_t)(cbase + c_l) * 4096 + m0 + moff);
                const float4 f0 = xp[0], f1 = xp[1], f2 = xp[2], f3 = xp[3];
                At[moff +  0][c_l] = f2bf(f0.x); At[moff +  1][c_l] = f2bf(f0.y);
                At[moff +  2][c_l] = f2bf(f0.z); At[moff +  3][c_l] = f2bf(f0.w);
                At[moff +  4][c_l] = f2bf(f1.x); At[moff +  5][c_l] = f2bf(f1.y);
                At[moff +  6][c_l] = f2bf(f1.z); At[moff +  7][c_l] = f2bf(f1.w);
                At[moff +  8][c_l] = f2bf(f2.x); At[moff +  9][c_l] = f2bf(f2.y);
                At[moff + 10][c_l] = f2bf(f2.z); At[moff + 11][c_l] = f2bf(f2.w);
                At[moff + 12][c_l] = f2bf(f3.x); At[moff + 13][c_l] = f2bf(f3.y);
                At[moff + 14][c_l] = f2bf(f3.z); At[moff + 15][c_l] = f2bf(f3.w);
            }
        }
        {
            const int o_l = tid >> 2, cp = (tid & 3) * 32;
            const float4* wp = reinterpret_cast<const float4*>(
                qw + (size_t)(o0 + o_l) * 256 + cbase + cp);
            #pragma unroll
            for (int j = 0; j < 2; ++j) {
                const float4 g0 = wp[4 * j + 0], g1 = wp[4 * j + 1];
                const float4 g2 = wp[4 * j + 2], g3 = wp[4 * j + 3];
                unsigned int u[8];
                u[0] = pk_bf16(g0.x, g0.y); u[1] = pk_bf16(g0.z, g0.w);
                u[2] = pk_bf16(g1.x, g1.y); u[3] = pk_bf16(g1.z, g1.w);
                u[4] = pk_bf16(g2.x, g2.y); u[5] = pk_bf16(g2.z, g2.w);
                u[6] = pk_bf16(g3.x, g3.y); u[7] = pk_bf16(g3.z, g3.w);
                __builtin_memcpy(&Wt[o_l][cp + 16 * j], u, 32);
            }
        }
        __syncthreads();
        #pragma unroll
        for (int cc = 0; cc < 4; ++cc) {
            const int c0 = cc * 32 + quad * 8;
            const short8 a = *reinterpret_cast<const short8*>(&At[wave * 16 + l16][c0]);
            #pragma unroll
            for (int t4 = 0; t4 < 4; ++t4) {
                const short8 b = *reinterpret_cast<const short8*>(&Wt[t4 * 16 + l16][c0]);
                acc[t4] = __builtin_amdgcn_mfma_f32_16x16x32_bf16(a, b, acc[t4], 0, 0, 0);
            }
        }
    }
    const float qscale = 0.17677669529663687f * L2E;
    #pragma unroll
    for (int t4 = 0; t4 < 4; ++t4) {
        #pragma unroll
        for (int r = 0; r < 4; ++r) {
            const int n = m0 + wave * 16 + quad * 4 + r;
            const int o = o0 + t4 * 16 + l16;
            const int s = o >> 8, rem = o & 255, head = rem >> 5, t = rem & 31;
            if (s == 0)       qm[((size_t)head * 4096 + n) * 32 + t] = f2bf(acc[t4][r] * qscale);
            else if (s == 1)  km[((size_t)head * 4096 + n) * 32 + t] = f2bf(acc[t4][r]);
            else              vt[((size_t)head * 32 + t) * 4096 + n] = f2bf(acc[t4][r]);
        }
    }
}

// ---------------- 2) flash attention: rectangular tile stream, branch-free body ----------------
// R18: two rounds proved the guarded-scan pipeline cannot be hoisted (loads are
// control-dependent on the scan result -> LLVM may not speculate them; VGPR 36/68,
// MfmaUtil ~5%, 75%+ idle). Fix the ROOT cause: the live-tile set is a clipped
// rectangle dk in [dq-9, dq+9]x4 h-groups; dead tiles already compute exactly P=0
// through the per-element dw2<thr cndmask. So enumerate tiles AFFINELY in a counted
// loop, load K/V UNCONDITIONALLY, and make the body branch-free straight-line
// (S-MFMA + exp + LDS ping-pong + PV-MFMA). ~35% more tile work, but the loop is a
// single basic block the scheduler can actually pipeline.
// 2 waves/block split tiles by parity (128 thr); 2048 blocks -> 16 waves/CU;
// launch_bounds(128,4) caps VGPR at 128 (need ~100 for 4x(K,V) short8 sets).
__global__ __launch_bounds__(128, 4) void k_attn(const unsigned short* __restrict__ qm,
                                                 const unsigned short* __restrict__ km,
                                                 const unsigned short* __restrict__ vt,
                                                 unsigned short* __restrict__ ao) {
    const int h   = blockIdx.y;
    const int nq0 = blockIdx.x * 16;
    const int tid = threadIdx.x;
    const int wv  = tid >> 6;                 // 0/1
    const int lane = tid & 63;
    const int l16 = lane & 15, quad = lane >> 4;

    __shared__ __align__(16) unsigned short PT[2][2][16][72];   // [wave][buf][q][key]

    // B-operand for S^T: Q^T (q on l16, k=c on quad*8+j)
    const short8 a_q = *reinterpret_cast<const short8*>(
        qm + ((size_t)h * 4096 + nq0 + l16) * 32 + quad * 8);

    const int hq = (nq0 >> 4) & 15, dq = nq0 >> 8;
    float dw2[4];
    #pragma unroll
    for (int r = 0; r < 4; ++r) {
        const float dw = (float)(quad * 4 + r - l16);   // key_w - q_w
        dw2[r] = dw * dw;
    }

    const unsigned short* kmh = km + ((size_t)h << 17) + l16 * 32 + quad * 8;
    const unsigned short* vt0 = vt + ((size_t)(h * 32 + l16) << 12) + quad * 8;
    const unsigned short* vt1 = vt0 + (16 << 12);

    float l_acc = 0.f;
    floatx4 o_acc[2] = {};

    const int dk_lo = (dq > 9) ? dq - 9 : 0;
    const int dk_hi = (dq < 6) ? dq + 9 : 15;
    const int ndk   = dk_hi - dk_lo + 1;      // 10..16
    // tiles T = 0..4*ndk-1; tile T -> dk = dk_lo + (T>>2), h-group g = T&3.
    // wave wv takes T ≡ wv (mod 2): NTw = 2*ndk tiles (even, >= 20).

// scalar tile parameters (SALU): thresholds + key base index
#define PARM(T, THR, J0)                                                  \
    {                                                                     \
        const int dk_ = dk_lo + ((T) >> 2);                               \
        const int g_  = (T) & 3;                                          \
        const int dd_ = dq - dk_;                                         \
        const int bb_ = 100 - dd_ * dd_;                                  \
        const int h0_ = hq - 4 * g_;                                      \
        J0 = dk_ * 256 + g_ * 64;                                         \
        THR[0] = bb_ - h0_ * h0_;                                         \
        THR[1] = bb_ - (h0_ - 1) * (h0_ - 1);                             \
        THR[2] = bb_ - (h0_ - 2) * (h0_ - 2);                             \
        THR[3] = bb_ - (h0_ - 3) * (h0_ - 3);                             \
    }

// unconditional K (4x short8) + V (4x short8) loads for a tile
#define LOADKV(J0, K, V)                                                  \
    {                                                                     \
        _Pragma("unroll")                                                 \
        for (int t4 = 0; t4 < 4; ++t4)                                    \
            K[t4] = *reinterpret_cast<const short8*>(                     \
                kmh + (((J0) + t4 * 16) << 5));                           \
        V[0] = *reinterpret_cast<const short8*>(vt0 + (J0));              \
        V[1] = *reinterpret_cast<const short8*>(vt1 + (J0));              \
        V[2] = *reinterpret_cast<const short8*>(vt0 + (J0) + 32);         \
        V[3] = *reinterpret_cast<const short8*>(vt1 + (J0) + 32);         \
    }

// branch-free S/exp/PT-write: dead sub-tiles produce P=0 via the cndmask
#define SSTAGE(THR, KB, BUF)                                              \
    {                                                                     \
        _Pragma("unroll")                                                 \
        for (int t4 = 0; t4 < 4; ++t4) {                                  \
            const floatx4 sf = __builtin_amdgcn_mfma_f32_16x16x32_bf16(   \
                KB[t4], a_q, (floatx4){0.f, 0.f, 0.f, 0.f}, 0, 0, 0);     \
            const float thrf = (float)THR[t4];                            \
            const float p0 = (dw2[0] < thrf) ? EXP2(sf[0]) : 0.f;         \
            const float p1 = (dw2[1] < thrf) ? EXP2(sf[1]) : 0.f;         \
            const float p2 = (dw2[2] < thrf) ? EXP2(sf[2]) : 0.f;         \
            const float p3 = (dw2[3] < thrf) ? EXP2(sf[3]) : 0.f;         \
            l_acc += (p0 + p1) + (p2 + p3);                               \
            unsigned int pair[2];                                         \
            pair[0] = pk_bf16(p0, p1);                                    \
            pair[1] = pk_bf16(p2, p3);                                    \
            __builtin_memcpy(&PT[wv][BUF][l16][t4 * 16 + quad * 4], pair, 8); \
        }                                                                 \
    }

// branch-free PV from buffer BUF with V-set VS
#define PV(VS, BUF)                                                       \
    {                                                                     \
        _Pragma("unroll")                                                 \
        for (int kt = 0; kt < 2; ++kt) {                                  \
            const short8 b_p = *reinterpret_cast<const short8*>(          \
                &PT[wv][BUF][l16][kt * 32 + quad * 8]);                   \
            o_acc[0] = __builtin_amdgcn_mfma_f32_16x16x32_bf16(           \
                VS[2 * kt], b_p, o_acc[0], 0, 0, 0);                      \
            o_acc[1] = __builtin_amdgcn_mfma_f32_16x16x32_bf16(           \
                VS[2 * kt + 1], b_p, o_acc[1], 0, 0, 0);                  \
        }                                                                 \
    }

    int thrA[4], j0A, thrB[4], j0B;
    short8 kA[4], vA[4], kB[4], vB[4];

    // prologue: tile T = wv
    PARM(wv, thrA, j0A)
    LOADKV(j0A, kA, vA)
    SSTAGE(thrA, kA, 0)

    int T = wv + 2;
    for (int it = ndk - 1; it > 0; --it) {          // (NTw-2)/2 iterations
        PARM(T, thrB, j0B)
        LOADKV(j0B, kB, vB)
        SSTAGE(thrB, kB, 1)
        PV(vA, 0)
        T += 2;
        PARM(T, thrA, j0A)
        LOADKV(j0A, kA, vA)
        SSTAGE(thrA, kA, 0)
        PV(vB, 1)
        T += 2;
    }
    // tail: last tile for this wave
    PARM(T, thrB, j0B)
    LOADKV(j0B, kB, vB)
    SSTAGE(thrB, kB, 1)
    PV(vA, 0)
    PV(vB, 1)

#undef PV
#undef SSTAGE
#undef LOADKV
#undef PARM

    // ---- epilogue: 2-wave combine through this block's PT smem ----
    // l: sum over quads (lanes sharing l16) -> every lane holds its wave's row sum
    l_acc += __shfl_xor(l_acc, 16);
    l_acc += __shfl_xor(l_acc, 32);

    float* fb = reinterpret_cast<float*>(&PT[wv][0][0][0]);   // 4608 B per wave region
    // layout: obuf[32][17] floats (2176 B) then lbuf[16] (64 B)
    #pragma unroll
    for (int tt = 0; tt < 2; ++tt)
        #pragma unroll
        for (int r = 0; r < 4; ++r)
            fb[(tt * 16 + quad * 4 + r) * 17 + l16] = o_acc[tt][r];
    if (lane < 16) fb[32 * 17 + l16] = l_acc;
    __syncthreads();

    // combine waves, normalize, write: q = tid&15, d0 = (tid>>4)*4 (4 d's per thread)
    const float* f0 = reinterpret_cast<const float*>(&PT[0][0][0][0]);
    const float* f1 = reinterpret_cast<const float*>(&PT[1][0][0][0]);
    const int q = tid & 15, d0 = (tid >> 4) * 4;
    const float lt = f0[32 * 17 + q] + f1[32 * 17 + q];
    const float inv = RCP(lt);
    const float oa = (f0[(d0 + 0) * 17 + q] + f1[(d0 + 0) * 17 + q]) * inv;
    const float ob = (f0[(d0 + 1) * 17 + q] + f1[(d0 + 1) * 17 + q]) * inv;
    const float oc = (f0[(d0 + 2) * 17 + q] + f1[(d0 + 2) * 17 + q]) * inv;
    const float od = (f0[(d0 + 3) * 17 + q] + f1[(d0 + 3) * 17 + q]) * inv;
    unsigned int uu[2];
    uu[0] = pk_bf16(oa, ob);
    uu[1] = pk_bf16(oc, od);
    __builtin_memcpy(ao + (size_t)(nq0 + q) * 256 + h * 32 + d0, uu, 8);
}

// ---------------- 3) proj GEMM + bias, self-staging pw (unchanged) ----------------
__global__ __launch_bounds__(256) void k_proj(const unsigned short* __restrict__ ao,
                                              const float* __restrict__ pw,
                                              const float* __restrict__ pb,
                                              float* __restrict__ out) {
    __shared__ __align__(16) unsigned short Pt[64][264];
    const int tid = threadIdx.x;
    const int wave = tid >> 6, lane = tid & 63;
    const int l16 = lane & 15, quad = lane >> 4;
    const int n0 = blockIdx.x * 64;
    const int m0 = blockIdx.y * 64;

    {
        const int o_l = tid >> 2, cp = (tid & 3) * 64;
        const float4* wp = reinterpret_cast<const float4*>(pw + (size_t)(m0 + o_l) * 256 + cp);
        #pragma unroll
        for (int j = 0; j < 4; ++j) {
            const float4 g0 = wp[4 * j + 0], g1 = wp[4 * j + 1];
            const float4 g2 = wp[4 * j + 2], g3 = wp[4 * j + 3];
            unsigned int u[8];
            u[0] = pk_bf16(g0.x, g0.y); u[1] = pk_bf16(g0.z, g0.w);
            u[2] = pk_bf16(g1.x, g1.y); u[3] = pk_bf16(g1.z, g1.w);
            u[4] = pk_bf16(g2.x, g2.y); u[5] = pk_bf16(g2.z, g2.w);
            u[6] = pk_bf16(g3.x, g3.y); u[7] = pk_bf16(g3.z, g3.w);
            __builtin_memcpy(&Pt[o_l][cp + 16 * j], u, 32);
        }
    }
    __syncthreads();

    floatx4 acc[4] = {};
    #pragma unroll
    for (int cc = 0; cc < 8; ++cc) {
        const int c0 = cc * 32 + quad * 8;
        const short8 a = *reinterpret_cast<const short8*>(&Pt[wave * 16 + l16][c0]);
        #pragma unroll
        for (int t4 = 0; t4 < 4; ++t4) {
            const short8 b = *reinterpret_cast<const short8*>(
                ao + (size_t)(n0 + t4 * 16 + l16) * 256 + c0);
            acc[t4] = __builtin_amdgcn_mfma_f32_16x16x32_bf16(a, b, acc[t4], 0, 0, 0);
        }
    }
    #pragma unroll
    for (int t4 = 0; t4 < 4; ++t4) {
        #pragma unroll
        for (int r = 0; r < 4; ++r) {
            const int o = m0 + wave * 16 + quad * 4 + r;
            const int n = n0 + t4 * 16 + l16;
            out[(size_t)o * 4096 + n] = acc[t4][r] + pb[o];
        }
    }
}

extern "C" void kernel_launch(void* const* d_in, const int* in_sizes, int n_in,
                              void* d_out, int out_size, void* d_ws, size_t ws_size,
                              hipStream_t stream) {
    const float* x      = (const float*)d_in[0];
    const float* qkv_w  = (const float*)d_in[1];
    const float* proj_w = (const float*)d_in[2];
    const float* proj_b = (const float*)d_in[3];
    float* out = (float*)d_out;                    // [256,4096] fp32

    char* B = (char*)d_ws;
    const size_t MB = 1u << 20;
    unsigned short* ao = (unsigned short*)(B);
    unsigned short* qm = (unsigned short*)(B + 2 * MB);
    unsigned short* km = (unsigned short*)(B + 4 * MB);
    unsigned short* vt = (unsigned short*)(B + 6 * MB);

    k_qkv<<<dim3(64, 12), 256, 0, stream>>>(x, qkv_w, qm, km, vt);
    k_attn<<<dim3(256, 8), 128, 0, stream>>>(qm, km, vt, ao);
    k_proj<<<dim3(64, 4), 256, 0, stream>>>(ao, proj_w, proj_b, out);
}

// Round 4
// 151.955 us; speedup vs baseline: 1.1197x; 1.1154x over previous
//
#include <hip/hip_runtime.h>
#include <hip/hip_bf16.h>

typedef __attribute__((ext_vector_type(8))) short short8;
typedef __attribute__((ext_vector_type(4))) float floatx4;

#define L2E 1.4426950408889634f

#if __has_builtin(__builtin_amdgcn_exp2f)
#define EXP2(x) __builtin_amdgcn_exp2f(x)
#else
#define EXP2(x) exp2f(x)
#endif
#if __has_builtin(__builtin_amdgcn_rcpf)
#define RCP(x) __builtin_amdgcn_rcpf(x)
#else
#define RCP(x) (1.0f / (x))
#endif

static __device__ __forceinline__ unsigned short f2bf(float f) {
    unsigned int u = __builtin_bit_cast(unsigned int, f);
    u += 0x7fffu + ((u >> 16) & 1u);   // RNE
    return (unsigned short)(u >> 16);
}
static __device__ __forceinline__ unsigned int pk_bf16(float a, float b) {
    __hip_bfloat162 h2 = __float22bfloat162_rn(make_float2(a, b));   // v_cvt_pk_bf16_f32
    unsigned int u;
    __builtin_memcpy(&u, &h2, 4);     // low16 = a, high16 = b
    return u;
}

// ---------------- 1) QKV GEMM, self-staging (unchanged) ----------------
__global__ __launch_bounds__(256) void k_qkv(const float* __restrict__ x,
                                             const float* __restrict__ qw,
                                             unsigned short* __restrict__ qm,
                                             unsigned short* __restrict__ km,
                                             unsigned short* __restrict__ vt) {
    __shared__ __align__(16) unsigned short At[64][136];
    __shared__ __align__(16) unsigned short Wt[64][136];
    const int tid = threadIdx.x;
    const int wave = tid >> 6, lane = tid & 63;
    const int l16 = lane & 15, quad = lane >> 4;
    const int m0 = blockIdx.x * 64;
    const int o0 = blockIdx.y * 64;

    floatx4 acc[4] = {};
    for (int rnd = 0; rnd < 2; ++rnd) {
        const int cbase = rnd * 128;
        if (rnd) __syncthreads();
        {
            const int moff = (tid & 3) * 16;
            #pragma unroll
            for (int half = 0; half < 2; ++half) {
                const int c_l = (tid >> 2) + 64 * half;
                const float4* xp = reinterpret_cast<const float4*>(
                    x + (size_t)(cbase + c_l) * 4096 + m0 + moff);
                const float4 f0 = xp[0], f1 = xp[1], f2 = xp[2], f3 = xp[3];
                At[moff +  0][c_l] = f2bf(f0.x); At[moff +  1][c_l] = f2bf(f0.y);
                At[moff +  2][c_l] = f2bf(f0.z); At[moff +  3][c_l] = f2bf(f0.w);
                At[moff +  4][c_l] = f2bf(f1.x); At[moff +  5][c_l] = f2bf(f1.y);
                At[moff +  6][c_l] = f2bf(f1.z); At[moff +  7][c_l] = f2bf(f1.w);
                At[moff +  8][c_l] = f2bf(f2.x); At[moff +  9][c_l] = f2bf(f2.y);
                At[moff + 10][c_l] = f2bf(f2.z); At[moff + 11][c_l] = f2bf(f2.w);
                At[moff + 12][c_l] = f2bf(f3.x); At[moff + 13][c_l] = f2bf(f3.y);
                At[moff + 14][c_l] = f2bf(f3.z); At[moff + 15][c_l] = f2bf(f3.w);
            }
        }
        {
            const int o_l = tid >> 2, cp = (tid & 3) * 32;
            const float4* wp = reinterpret_cast<const float4*>(
                qw + (size_t)(o0 + o_l) * 256 + cbase + cp);
            #pragma unroll
            for (int j = 0; j < 2; ++j) {
                const float4 g0 = wp[4 * j + 0], g1 = wp[4 * j + 1];
                const float4 g2 = wp[4 * j + 2], g3 = wp[4 * j + 3];
                unsigned int u[8];
                u[0] = pk_bf16(g0.x, g0.y); u[1] = pk_bf16(g0.z, g0.w);
                u[2] = pk_bf16(g1.x, g1.y); u[3] = pk_bf16(g1.z, g1.w);
                u[4] = pk_bf16(g2.x, g2.y); u[5] = pk_bf16(g2.z, g2.w);
                u[6] = pk_bf16(g3.x, g3.y); u[7] = pk_bf16(g3.z, g3.w);
                __builtin_memcpy(&Wt[o_l][cp + 16 * j], u, 32);
            }
        }
        __syncthreads();
        #pragma unroll
        for (int cc = 0; cc < 4; ++cc) {
            const int c0 = cc * 32 + quad * 8;
            const short8 a = *reinterpret_cast<const short8*>(&At[wave * 16 + l16][c0]);
            #pragma unroll
            for (int t4 = 0; t4 < 4; ++t4) {
                const short8 b = *reinterpret_cast<const short8*>(&Wt[t4 * 16 + l16][c0]);
                acc[t4] = __builtin_amdgcn_mfma_f32_16x16x32_bf16(a, b, acc[t4], 0, 0, 0);
            }
        }
    }
    const float qscale = 0.17677669529663687f * L2E;
    #pragma unroll
    for (int t4 = 0; t4 < 4; ++t4) {
        #pragma unroll
        for (int r = 0; r < 4; ++r) {
            const int n = m0 + wave * 16 + quad * 4 + r;
            const int o = o0 + t4 * 16 + l16;
            const int s = o >> 8, rem = o & 255, head = rem >> 5, t = rem & 31;
            if (s == 0)       qm[((size_t)head * 4096 + n) * 32 + t] = f2bf(acc[t4][r] * qscale);
            else if (s == 1)  km[((size_t)head * 4096 + n) * 32 + t] = f2bf(acc[t4][r]);
            else              vt[((size_t)head * 32 + t) * 4096 + n] = f2bf(acc[t4][r]);
        }
    }
}

// ---------------- 2) flash attention: LDS-shared K/V tiles, 2-phase double buffer ----------------
// R19: three schedule rewrites all landed ~90us (MfmaUtil 5%, VALUBusy 25%, HBM 3%)
// -> bottleneck is the DATA FLOW: 2048 blocks each stream ~440KB of K/V through
// L1/L2 (900MB of L2 requests, zero reuse). Restructure: block = 64 q-rows x 1 head
// (4 waves, one 16-row q-tile each). All waves share the same dq -> identical
// rectangular (dk,g) tile list -> stage each K/V tile ONCE into LDS (reg-staged
// double-buffer, loads issued one full tile ahead; prefetch state = 8 VGPRs so
// regalloc cannot sink it). Global traffic /4; fragment reads become LDS with
// conflict-free swizzled layouts:
//   Kt linear [64 keys][32 dims] ^ ((key&7)<<3)  (slot spread, T2 recipe)
//   Vt tiled  [8 keygroups][32 dims][8 keys] ^ (kg<<3)
// Per-wave dead tiles (~35%) skip compute under a wave-uniform branch; staging and
// barriers stay uniform. Epilogue: direct per-wave write (waves own disjoint rows).
__global__ __launch_bounds__(256, 2) void k_attn(const unsigned short* __restrict__ qm,
                                                 const unsigned short* __restrict__ km,
                                                 const unsigned short* __restrict__ vt,
                                                 unsigned short* __restrict__ ao) {
    const int h   = blockIdx.y;
    const int nq0 = blockIdx.x * 64;          // 64 q-rows per block (same dq for all)
    const int tid = threadIdx.x;
    const int wv  = tid >> 6;                 // wave owns q-tile nq0 + wv*16
    const int lane = tid & 63;
    const int l16 = lane & 15, quad = lane >> 4;
    const int nqw = nq0 + wv * 16;

    __shared__ __align__(16) unsigned short Kt[2][2048];   // [buf][key*32+dim ^ swz]
    __shared__ __align__(16) unsigned short Vt[2][2048];   // [buf][kg*256+dim*8 ^ swz]
    __shared__ __align__(16) unsigned short PT[4][16][72]; // per-wave P^T scratch

    // B-operand for S^T: Q^T (q on l16, k=c on quad*8+j)
    const short8 a_q = *reinterpret_cast<const short8*>(
        qm + ((size_t)h * 4096 + nqw + l16) * 32 + quad * 8);

    const int hq = (nqw >> 4) & 15;           // per-wave h-coordinate
    const int dq = nq0 >> 8;                  // block-uniform d-coordinate
    float dw2[4];
    #pragma unroll
    for (int r = 0; r < 4; ++r) {
        const float dw = (float)(quad * 4 + r - l16);   // key_w - q_w
        dw2[r] = dw * dw;
    }

    const int dk_lo = (dq > 9) ? dq - 9 : 0;
    const int dk_hi = (dq < 6) ? dq + 9 : 15;
    const int NT = 4 * (dk_hi - dk_lo + 1);   // 40..64 tiles, all waves do all tiles

    // staging roles (256 threads move one 4KB K-tile + 4KB V-tile)
    const int skey = tid >> 2;                // K: key 0..63
    const int sdo  = (tid & 3) * 8;           //    dim offset 0/8/16/24
    const int sdim = tid >> 3;                // V: dim 0..31
    const int skg  = tid & 7;                 //    keygroup 0..7
    const unsigned short* ksrc = km + ((size_t)h << 17) + skey * 32 + sdo;
    const unsigned short* vsrc = vt + (((size_t)h * 32 + sdim) << 12) + skg * 8;
    const int kdst = (skey * 32 + sdo) ^ ((skey & 7) << 3);
    const int vdst = (skg * 256 + sdim * 8) ^ (skg << 3);

    float l_acc = 0.f;
    floatx4 o_acc[2] = {};

#define J0T(T) (((dk_lo + ((T) >> 2)) << 8) + (((T) & 3) << 6))

    // ---- prologue: tile 0 -> buf 0; tile 1 -> regs ----
    short8 gK, gV;
    {
        const int j0 = J0T(0);
        gK = *reinterpret_cast<const short8*>(ksrc + (size_t)j0 * 32);
        gV = *reinterpret_cast<const short8*>(vsrc + j0);
        *reinterpret_cast<short8*>(&Kt[0][kdst]) = gK;
        *reinterpret_cast<short8*>(&Vt[0][vdst]) = gV;
        const int j1 = J0T(1);
        gK = *reinterpret_cast<const short8*>(ksrc + (size_t)j1 * 32);
        gV = *reinterpret_cast<const short8*>(vsrc + j1);
    }
    __syncthreads();

    for (int t = 0; t < NT; ++t) {
        const int cb = t & 1, nb = cb ^ 1;

        // (A) write tile t+1 (held in regs) into the other buffer
        *reinterpret_cast<short8*>(&Kt[nb][kdst]) = gK;
        *reinterpret_cast<short8*>(&Vt[nb][vdst]) = gV;

        // (B) prefetch tile t+2 into regs (clamped; load->use = one full iteration)
        {
            const int tn = (t + 2 < NT) ? t + 2 : NT - 1;
            const int j2 = J0T(tn);
            gK = *reinterpret_cast<const short8*>(ksrc + (size_t)j2 * 32);
            gV = *reinterpret_cast<const short8*>(vsrc + j2);
        }

        // (C) per-wave compute on tile t from buf cb
        {
            const int dk = dk_lo + (t >> 2), g = t & 3;
            const int dd = dq - dk;
            const int bb = 100 - dd * dd;
            const int h0 = hq - 4 * g;
            int thr[4];
            thr[0] = bb - h0 * h0;
            thr[1] = bb - (h0 - 1) * (h0 - 1);
            thr[2] = bb - (h0 - 2) * (h0 - 2);
            thr[3] = bb - (h0 - 3) * (h0 - 3);

            if (thr[0] > 0 || thr[1] > 0 || thr[2] > 0 || thr[3] > 0) {
                // S stage: K frags from LDS, MFMA, exp, P^T to per-wave scratch
                #pragma unroll
                for (int t4 = 0; t4 < 4; ++t4) {
                    const bool sib = (thr[t4 ^ 1] > 0);
                    if (thr[t4] > 0) {
                        const short8 kf = *reinterpret_cast<const short8*>(
                            &Kt[cb][((t4 * 16 + l16) * 32 + quad * 8) ^ ((l16 & 7) << 3)]);
                        const floatx4 sf = __builtin_amdgcn_mfma_f32_16x16x32_bf16(
                            kf, a_q, (floatx4){0.f, 0.f, 0.f, 0.f}, 0, 0, 0);
                        const float thrf = (float)thr[t4];
                        const float p0 = (dw2[0] < thrf) ? EXP2(sf[0]) : 0.f;
                        const float p1 = (dw2[1] < thrf) ? EXP2(sf[1]) : 0.f;
                        const float p2 = (dw2[2] < thrf) ? EXP2(sf[2]) : 0.f;
                        const float p3 = (dw2[3] < thrf) ? EXP2(sf[3]) : 0.f;
                        l_acc += (p0 + p1) + (p2 + p3);
                        unsigned int pair[2];
                        pair[0] = pk_bf16(p0, p1);
                        pair[1] = pk_bf16(p2, p3);
                        __builtin_memcpy(&PT[wv][l16][t4 * 16 + quad * 4], pair, 8);
                    } else if (sib) {
                        const unsigned int zz[2] = {0u, 0u};
                        __builtin_memcpy(&PT[wv][l16][t4 * 16 + quad * 4], zz, 8);
                    }
                }
                // PV: V frags from LDS
                #pragma unroll
                for (int kt = 0; kt < 2; ++kt) {
                    if (thr[2 * kt] > 0 || thr[2 * kt + 1] > 0) {
                        const short8 b_p = *reinterpret_cast<const short8*>(
                            &PT[wv][l16][kt * 32 + quad * 8]);
                        const int kg = kt * 4 + quad;
                        #pragma unroll
                        for (int hf = 0; hf < 2; ++hf) {
                            const short8 vf = *reinterpret_cast<const short8*>(
                                &Vt[cb][(kg * 256 + (hf * 16 + l16) * 8) ^ (kg << 3)]);
                            o_acc[hf] = __builtin_amdgcn_mfma_f32_16x16x32_bf16(
                                vf, b_p, o_acc[hf], 0, 0, 0);
                        }
                    }
                }
            }
        }
        __syncthreads();
    }
#undef J0T

    // ---- epilogue: waves own disjoint q-rows; direct write ----
    l_acc += __shfl_xor(l_acc, 16);
    l_acc += __shfl_xor(l_acc, 32);
    const float inv = RCP(l_acc);
    #pragma unroll
    for (int hf = 0; hf < 2; ++hf) {
        unsigned int uu[2];
        uu[0] = pk_bf16(o_acc[hf][0] * inv, o_acc[hf][1] * inv);
        uu[1] = pk_bf16(o_acc[hf][2] * inv, o_acc[hf][3] * inv);
        __builtin_memcpy(ao + (size_t)(nqw + l16) * 256 + h * 32 + hf * 16 + quad * 4,
                         uu, 8);
    }
}

// ---------------- 3) proj GEMM + bias, self-staging pw (unchanged) ----------------
__global__ __launch_bounds__(256) void k_proj(const unsigned short* __restrict__ ao,
                                              const float* __restrict__ pw,
                                              const float* __restrict__ pb,
                                              float* __restrict__ out) {
    __shared__ __align__(16) unsigned short Pt[64][264];
    const int tid = threadIdx.x;
    const int wave = tid >> 6, lane = tid & 63;
    const int l16 = lane & 15, quad = lane >> 4;
    const int n0 = blockIdx.x * 64;
    const int m0 = blockIdx.y * 64;

    {
        const int o_l = tid >> 2, cp = (tid & 3) * 64;
        const float4* wp = reinterpret_cast<const float4*>(pw + (size_t)(m0 + o_l) * 256 + cp);
        #pragma unroll
        for (int j = 0; j < 4; ++j) {
            const float4 g0 = wp[4 * j + 0], g1 = wp[4 * j + 1];
            const float4 g2 = wp[4 * j + 2], g3 = wp[4 * j + 3];
            unsigned int u[8];
            u[0] = pk_bf16(g0.x, g0.y); u[1] = pk_bf16(g0.z, g0.w);
            u[2] = pk_bf16(g1.x, g1.y); u[3] = pk_bf16(g1.z, g1.w);
            u[4] = pk_bf16(g2.x, g2.y); u[5] = pk_bf16(g2.z, g2.w);
            u[6] = pk_bf16(g3.x, g3.y); u[7] = pk_bf16(g3.z, g3.w);
            __builtin_memcpy(&Pt[o_l][cp + 16 * j], u, 32);
        }
    }
    __syncthreads();

    floatx4 acc[4] = {};
    #pragma unroll
    for (int cc = 0; cc < 8; ++cc) {
        const int c0 = cc * 32 + quad * 8;
        const short8 a = *reinterpret_cast<const short8*>(&Pt[wave * 16 + l16][c0]);
        #pragma unroll
        for (int t4 = 0; t4 < 4; ++t4) {
            const short8 b = *reinterpret_cast<const short8*>(
                ao + (size_t)(n0 + t4 * 16 + l16) * 256 + c0);
            acc[t4] = __builtin_amdgcn_mfma_f32_16x16x32_bf16(a, b, acc[t4], 0, 0, 0);
        }
    }
    #pragma unroll
    for (int t4 = 0; t4 < 4; ++t4) {
        #pragma unroll
        for (int r = 0; r < 4; ++r) {
            const int o = m0 + wave * 16 + quad * 4 + r;
            const int n = n0 + t4 * 16 + l16;
            out[(size_t)o * 4096 + n] = acc[t4][r] + pb[o];
        }
    }
}

extern "C" void kernel_launch(void* const* d_in, const int* in_sizes, int n_in,
                              void* d_out, int out_size, void* d_ws, size_t ws_size,
                              hipStream_t stream) {
    const float* x      = (const float*)d_in[0];
    const float* qkv_w  = (const float*)d_in[1];
    const float* proj_w = (const float*)d_in[2];
    const float* proj_b = (const float*)d_in[3];
    float* out = (float*)d_out;                    // [256,4096] fp32

    char* B = (char*)d_ws;
    const size_t MB = 1u << 20;
    unsigned short* ao = (unsigned short*)(B);
    unsigned short* qm = (unsigned short*)(B + 2 * MB);
    unsigned short* km = (unsigned short*)(B + 4 * MB);
    unsigned short* vt = (unsigned short*)(B + 6 * MB);

    k_qkv<<<dim3(64, 12), 256, 0, stream>>>(x, qkv_w, qm, km, vt);
    k_attn<<<dim3(64, 8), 256, 0, stream>>>(qm, km, vt, ao);
    k_proj<<<dim3(64, 4), 256, 0, stream>>>(ao, proj_w, proj_b, out);
}